// Round 7
// baseline (206.823 us; speedup 1.0000x reference)
//
#include <hip/hip_runtime.h>

typedef unsigned short u16;
typedef unsigned int u32;
typedef __bf16 bf16x2 __attribute__((ext_vector_type(2)));
typedef __bf16 bf16x8 __attribute__((ext_vector_type(8)));
typedef float f32x4 __attribute__((ext_vector_type(4)));
typedef float f32x16 __attribute__((ext_vector_type(16)));

#define BB 2
#define TT 2048
#define CC 1024
#define HH 16
#define DD 64
#define MR (BB*TT)   // 4096
#define NQ (3*CC)    // 3072
#define SCQ 0.18033688f   // 0.125 * log2(e), folded into Q

__device__ __forceinline__ u16 f2b(float f) {
    __bf16 h = (__bf16)f;
    return __builtin_bit_cast(u16, h);
}
__device__ __forceinline__ float b2f(u16 b) {
    return __builtin_bit_cast(float, (u32)b << 16);
}
__device__ __forceinline__ u32 pkbf(float a, float b) {
    bf16x2 t; t[0] = (__bf16)a; t[1] = (__bf16)b;
    return __builtin_bit_cast(u32, t);
}

__device__ __forceinline__ void gll16(const void* g, void* l) {
    __builtin_amdgcn_global_load_lds(
        (const __attribute__((address_space(1))) void*)g,
        (__attribute__((address_space(3))) void*)l,
        16, 0, 0);
}

// ------- fused fp32->bf16 convert (x, Wqkv, Wproj) + rope table + counter zero -------
__global__ void cvt_all(const float* __restrict__ x, const float* __restrict__ wqkv,
                        const float* __restrict__ wproj,
                        u16* __restrict__ xb, u16* __restrict__ wqkvb, u16* __restrict__ wprojb,
                        float2* __restrict__ tab, u32* __restrict__ ctr)
{
    if (blockIdx.x == 0 && threadIdx.x == 0) *ctr = 0;
    const int n0 = MR * CC / 4, n1 = NQ * CC / 4, n2 = CC * CC / 4;
    int i = blockIdx.x * 256 + threadIdx.x;
    if (i < n0 + n1 + n2) {
        const float* src; u16* dst; int off;
        if (i < n0)           { src = x;     dst = xb;     off = i; }
        else if (i < n0 + n1) { src = wqkv;  dst = wqkvb;  off = i - n0; }
        else                  { src = wproj; dst = wprojb; off = i - n0 - n1; }
        float4 v = reinterpret_cast<const float4*>(src)[off];
        ushort4 o;
        o.x = f2b(v.x); o.y = f2b(v.y); o.z = f2b(v.z); o.w = f2b(v.w);
        reinterpret_cast<ushort4*>(dst)[off] = o;
    } else {
        const int e = i - (n0 + n1 + n2);
        if (e < TT * 32) {
            const int t = e >> 5, j = e & 31;
            const float theta = expf((float)(2 * j) * (-0.14391157f)); // -ln(1e4)/64
            float s, c;
            sincosf((float)t * theta, &s, &c);
            tab[e] = make_float2(c, s);
        }
    }
}

// ------- QKV GEMM (m97 structure) + fused bias + RoPE + scatter epilogue -------
__global__ __launch_bounds__(256) void gemm_qkv(
    const u16* __restrict__ A, const u16* __restrict__ Bm,
    const float* __restrict__ bias, const float2* __restrict__ tab,
    u16* __restrict__ Qr, u16* __restrict__ Kr, u16* __restrict__ Vc)
{
    __shared__ __align__(16) u16 As[128 * 32];
    __shared__ __align__(16) u16 Bs[128 * 32];
    const int K = CC;
    const int tid = threadIdx.x;
    const int lane = tid & 63;
    const int w = tid >> 6;
    const int wr = w >> 1, wc = w & 1;
    const int fr = lane & 15, fq = lane >> 4;
    // bijective XCD swizzle: nwg = 768 = 8 * 96
    const int orig = blockIdx.y * 24 + blockIdx.x;
    const int wg = (orig & 7) * 96 + (orig >> 3);
    const int brow = (wg / 24) * 128, bcol = (wg % 24) * 128;
    const int srow = lane >> 2;
    const int scol = (lane & 3) * 8;

    f32x4 acc[4][4];
    const f32x4 zero = {0.f, 0.f, 0.f, 0.f};
#pragma unroll
    for (int i = 0; i < 4; i++)
#pragma unroll
        for (int j = 0; j < 4; j++) acc[i][j] = zero;

    for (int kt = 0; kt < K; kt += 32) {
#pragma unroll
        for (int i = 0; i < 2; i++) {
            const int r = i * 64 + w * 16 + srow;
            gll16(&A[(size_t)(brow + r) * K + kt + scol], &As[(i * 64 + w * 16) * 32]);
            gll16(&Bm[(size_t)(bcol + r) * K + kt + scol], &Bs[(i * 64 + w * 16) * 32]);
        }
        __syncthreads();
        bf16x8 af[4], bfr[4];
#pragma unroll
        for (int mi = 0; mi < 4; mi++)
            af[mi] = *reinterpret_cast<const bf16x8*>(&As[(wr * 64 + mi * 16 + fr) * 32 + fq * 8]);
#pragma unroll
        for (int nj = 0; nj < 4; nj++)
            bfr[nj] = *reinterpret_cast<const bf16x8*>(&Bs[(wc * 64 + nj * 16 + fr) * 32 + fq * 8]);
#pragma unroll
        for (int mi = 0; mi < 4; mi++)
#pragma unroll
            for (int nj = 0; nj < 4; nj++)
                acc[mi][nj] = __builtin_amdgcn_mfma_f32_16x16x32_bf16(af[mi], bfr[nj], acc[mi][nj], 0, 0, 0);
        __syncthreads();
    }

    // epilogue: bias + rope + scatter
#pragma unroll
    for (int mi = 0; mi < 4; mi++) {
#pragma unroll
        for (int nj = 0; nj < 4; nj++) {
            const int n = bcol + wc * 64 + nj * 16 + fr;
            const float bn = bias[n];
            const int sec = n >> 10;          // 0=Q 1=K 2=V (fragment-uniform)
            const int h = (n >> 6) & 15;
            const int d = n & 63;
            const int j = d >> 1;
            const bool odd = d & 1;
#pragma unroll
            for (int r = 0; r < 4; r++) {
                const int m = brow + wr * 64 + mi * 16 + fq * 4 + r;
                const int b = m >> 11, t = m & 2047;
                const float v = acc[mi][nj][r] + bn;
                const float p = __shfl_xor(v, 1);
                if (sec == 2) {
                    Vc[(size_t)m * CC + (n - 2 * CC)] = f2b(v);
                } else {
                    const float2 cs = tab[t * 32 + j];
                    const float o = odd ? (v * cs.x + p * cs.y) : (v * cs.x - p * cs.y);
                    const size_t oidx = ((size_t)(b * HH + h) * TT + t) * DD + d;
                    if (sec == 0) Qr[oidx] = f2b(o * SCQ);
                    else          Kr[oidx] = f2b(o);
                }
            }
        }
    }
}

// ------- proj GEMM: 64x128 tile (2 blocks/CU to hide barrier drain), fp32 out -------
__global__ __launch_bounds__(256) void gemm_proj(
    const u16* __restrict__ A, const u16* __restrict__ Bm,
    const float* __restrict__ bias, float* __restrict__ outp)
{
    __shared__ __align__(16) u16 As[64 * 32];
    __shared__ __align__(16) u16 Bs[128 * 32];
    const int M = MR, N = CC, K = CC;
    const int tid = threadIdx.x;
    const int lane = tid & 63;
    const int w = tid >> 6;
    const int fr = lane & 15, fq = lane >> 4;
    // bijective XCD swizzle: nwg = 512 = 8 * 64
    const int orig = blockIdx.y * 8 + blockIdx.x;
    const int wg = (orig & 7) * 64 + (orig >> 3);
    const int brow = (wg >> 3) * 64, bcol = (wg & 7) * 128;
    const int srow = lane >> 2;
    const int scol = (lane & 3) * 8;

    f32x4 acc[4][2];
    const f32x4 zero = {0.f, 0.f, 0.f, 0.f};
#pragma unroll
    for (int i = 0; i < 4; i++)
#pragma unroll
        for (int j = 0; j < 2; j++) acc[i][j] = zero;

    for (int kt = 0; kt < K; kt += 32) {
        gll16(&A[(size_t)(brow + w * 16 + srow) * K + kt + scol], &As[(w * 16) * 32]);
#pragma unroll
        for (int i = 0; i < 2; i++)
            gll16(&Bm[(size_t)(bcol + i * 64 + w * 16 + srow) * K + kt + scol],
                  &Bs[(i * 64 + w * 16) * 32]);
        __syncthreads();
        bf16x8 af[4], bfr[2];
#pragma unroll
        for (int mi = 0; mi < 4; mi++)
            af[mi] = *reinterpret_cast<const bf16x8*>(&As[(mi * 16 + fr) * 32 + fq * 8]);
#pragma unroll
        for (int nj = 0; nj < 2; nj++)
            bfr[nj] = *reinterpret_cast<const bf16x8*>(&Bs[(w * 32 + nj * 16 + fr) * 32 + fq * 8]);
#pragma unroll
        for (int mi = 0; mi < 4; mi++)
#pragma unroll
            for (int nj = 0; nj < 2; nj++)
                acc[mi][nj] = __builtin_amdgcn_mfma_f32_16x16x32_bf16(af[mi], bfr[nj], acc[mi][nj], 0, 0, 0);
        __syncthreads();
    }

#pragma unroll
    for (int mi = 0; mi < 4; mi++) {
#pragma unroll
        for (int nj = 0; nj < 2; nj++) {
            const int n = bcol + w * 32 + nj * 16 + fr;
            const float bn = bias[n];
#pragma unroll
            for (int r = 0; r < 4; r++) {
                const int m = brow + mi * 16 + fq * 4 + r;
                outp[(size_t)m * N + n] = acc[mi][nj][r] + bn;
            }
        }
    }
}

// ---------------- V transpose: Vc (B,T,C) -> Vt (B,H,D,T) ----------------
__global__ __launch_bounds__(64) void vtrans(const u16* __restrict__ Vc, u16* __restrict__ Vtg)
{
    const int lane = threadIdx.x;
    const int t0 = blockIdx.x * 64;
    const int bh = blockIdx.y;
    const int b = bh >> 4, h = bh & 15;
    u32 packed[32];
#pragma unroll
    for (int tt = 0; tt < 64; tt += 2) {
        const u16 a = Vc[(size_t)(b * TT + t0 + tt) * CC + h * DD + lane];
        const u16 c = Vc[(size_t)(b * TT + t0 + tt + 1) * CC + h * DD + lane];
        packed[tt >> 1] = (u32)a | ((u32)c << 16);
    }
    u32* dst = reinterpret_cast<u32*>(&Vtg[((size_t)bh * DD + lane) * TT + t0]);
#pragma unroll
    for (int i = 0; i < 32; i += 4)
        *reinterpret_cast<uint4*>(&dst[i]) = make_uint4(packed[i], packed[i + 1], packed[i + 2], packed[i + 3]);
}

// ---------------- causal flash attention: persistent + queue + KV-split ----------------
// grid 768 (idle blocks exit via queue) -> ~2 working blocks/CU, 4 waves/SIMD.
__global__ __launch_bounds__(512) void attn_fwd(
    const u16* __restrict__ Q, const u16* __restrict__ Kg, const u16* __restrict__ Vtg,
    u16* __restrict__ Y, u32* __restrict__ ctr)
{
    __shared__ __align__(16) u16 smem[4 * 64 * 72];
    __shared__ int cur;
    const int tid = threadIdx.x;
    const int lane = tid & 63;
    const int ql = lane & 31;
    const int hB = lane >> 5;
    const int wq = (tid >> 6) & 3;
    const int g  = tid >> 8;
    const int srow = (tid & 255) >> 2;
    const int sc   = tid & 3;
    u16* KsG = smem + (g * 2 + 0) * 4608;
    u16* VsG = smem + (g * 2 + 1) * 4608;
    float* fm = reinterpret_cast<float*>(smem);

    while (true) {
        if (tid == 0) cur = atomicAdd(ctr, 1);
        __syncthreads();
        const int it = cur;
        __syncthreads();
        if (it >= 512) break;

        const int bx = 15 - (it >> 5);
        const int bh = it & 31;
        const int q0 = bx << 7;
        const int halfL = bx + 1;
        const int b = bh >> 4, hh = bh & 15;
        const int qb = q0 + wq * 32;
        const int qg = qb + ql;
        const size_t base  = (size_t)bh * TT * DD;
        const size_t vbase = (size_t)bh * DD * TT;

        bf16x8 qf[4];
#pragma unroll
        for (int ds = 0; ds < 4; ds++)
            qf[ds] = *reinterpret_cast<const bf16x8*>(&Q[base + (size_t)qg * DD + ds * 16 + hB * 8]);

        f32x16 acc[2];
#pragma unroll
        for (int dh = 0; dh < 2; dh++)
#pragma unroll
            for (int r = 0; r < 16; r++) acc[dh][r] = 0.f;
        float m_ = -1e30f, l_ = 0.f;

        int kv0 = 64 * g;
        uint4 kr0, kr1, vr0, vr1;
        {
            const size_t kro = base + (size_t)(kv0 + srow) * DD;
            kr0 = *reinterpret_cast<const uint4*>(&Kg[kro + sc * 8]);
            kr1 = *reinterpret_cast<const uint4*>(&Kg[kro + 32 + sc * 8]);
            const size_t vro = vbase + (size_t)srow * TT + kv0;
            vr0 = *reinterpret_cast<const uint4*>(&Vtg[vro + sc * 8]);
            vr1 = *reinterpret_cast<const uint4*>(&Vtg[vro + 32 + sc * 8]);
        }

        for (int i = 0; i < halfL; ++i) {
            *reinterpret_cast<uint4*>(&KsG[srow * 72 + sc * 8])      = kr0;
            *reinterpret_cast<uint4*>(&KsG[srow * 72 + 32 + sc * 8]) = kr1;
            *reinterpret_cast<uint4*>(&VsG[srow * 72 + sc * 8])      = vr0;
            *reinterpret_cast<uint4*>(&VsG[srow * 72 + 32 + sc * 8]) = vr1;
            if (i + 1 < halfL) {
                const size_t kro = base + (size_t)(kv0 + 128 + srow) * DD;
                kr0 = *reinterpret_cast<const uint4*>(&Kg[kro + sc * 8]);
                kr1 = *reinterpret_cast<const uint4*>(&Kg[kro + 32 + sc * 8]);
                const size_t vro = vbase + (size_t)srow * TT + kv0 + 128;
                vr0 = *reinterpret_cast<const uint4*>(&Vtg[vro + sc * 8]);
                vr1 = *reinterpret_cast<const uint4*>(&Vtg[vro + 32 + sc * 8]);
            }
            __syncthreads();

            if (kv0 <= qb + 31) {
                f32x16 sa[2];
#pragma unroll
                for (int st = 0; st < 2; st++)
#pragma unroll
                    for (int r = 0; r < 16; r++) sa[st][r] = 0.f;
                __builtin_amdgcn_s_setprio(1);
#pragma unroll
                for (int st = 0; st < 2; st++)
#pragma unroll
                    for (int ds = 0; ds < 4; ds++) {
                        bf16x8 kf = *reinterpret_cast<const bf16x8*>(
                            &KsG[(st * 32 + ql) * 72 + ds * 16 + hB * 8]);
                        sa[st] = __builtin_amdgcn_mfma_f32_32x32x16_bf16(kf, qf[ds], sa[st], 0, 0, 0);
                    }
                __builtin_amdgcn_s_setprio(0);
                if (kv0 + 63 > qb) {
#pragma unroll
                    for (int st = 0; st < 2; st++) {
                        const int kb0 = kv0 + st * 32 + 4 * hB;
#pragma unroll
                        for (int r = 0; r < 16; r++) {
                            const int kg = kb0 + (r & 3) + 8 * (r >> 2);
                            if (kg > qg) sa[st][r] = -1e30f;
                        }
                    }
                }
                // row max: pairwise then max3-shaped tree (v_max3_f32 fusion)
                float mx[16];
#pragma unroll
                for (int j = 0; j < 16; j++) mx[j] = fmaxf(sa[0][j], sa[1][j]);
                const float r0 = fmaxf(fmaxf(mx[0], mx[1]), mx[2]);
                const float r1 = fmaxf(fmaxf(mx[3], mx[4]), mx[5]);
                const float r2 = fmaxf(fmaxf(mx[6], mx[7]), mx[8]);
                const float r3 = fmaxf(fmaxf(mx[9], mx[10]), mx[11]);
                const float r4 = fmaxf(fmaxf(mx[12], mx[13]), mx[14]);
                const float r5 = fmaxf(fmaxf(r0, r1), r2);
                const float r6 = fmaxf(fmaxf(r3, r4), mx[15]);
                float tm = fmaxf(r5, r6);
                tm = fmaxf(tm, __shfl_xor(tm, 32));
                // defer-max (T13, THR=8 in log2 domain): only rescale when the
                // running max grows by >8 -> P bounded by 2^8, l_/acc exact re-norm
                const bool need = __any(tm > m_ + 8.0f);
                float scl = 1.0f;
                if (need) {
                    const float mn = fmaxf(m_, tm);
                    scl = exp2f(m_ - mn);
                    m_ = mn;
                }
#pragma unroll
                for (int st = 0; st < 2; st++)
#pragma unroll
                    for (int r = 0; r < 16; r++)
                        sa[st][r] = exp2f(sa[st][r] - m_);
                float ps[16];
#pragma unroll
                for (int j = 0; j < 16; j++) ps[j] = sa[0][j] + sa[1][j];
#pragma unroll
                for (int j = 0; j < 8; j++) ps[j] += ps[j + 8];
#pragma unroll
                for (int j = 0; j < 4; j++) ps[j] += ps[j + 4];
                float rs = (ps[0] + ps[1]) + (ps[2] + ps[3]);
                rs += __shfl_xor(rs, 32);
                if (need) {
                    l_ = l_ * scl + rs;
#pragma unroll
                    for (int dh = 0; dh < 2; dh++)
#pragma unroll
                        for (int r = 0; r < 16; r++) acc[dh][r] *= scl;
                } else {
                    l_ += rs;
                }
                // pack P (native cvt_pk) then permlane to A-frag, PV
                u32 pk[2][8];
#pragma unroll
                for (int st = 0; st < 2; st++)
#pragma unroll
                    for (int wd = 0; wd < 8; wd++)
                        pk[st][wd] = pkbf(sa[st][2 * wd], sa[st][2 * wd + 1]);
                __builtin_amdgcn_s_setprio(1);
#pragma unroll
                for (int c = 0; c < 4; c++) {
                    u32 a0 = pk[c >> 1][4 * (c & 1) + 0];
                    u32 a1 = pk[c >> 1][4 * (c & 1) + 1];
                    u32 a2 = pk[c >> 1][4 * (c & 1) + 2];
                    u32 a3 = pk[c >> 1][4 * (c & 1) + 3];
                    asm volatile("v_permlane32_swap_b32 %0, %1" : "+v"(a0), "+v"(a2));
                    asm volatile("v_permlane32_swap_b32 %0, %1" : "+v"(a1), "+v"(a3));
                    uint4 tw = make_uint4(a0, a1, a2, a3);
                    bf16x8 pb = __builtin_bit_cast(bf16x8, tw);
#pragma unroll
                    for (int dh = 0; dh < 2; dh++) {
                        bf16x8 vf = *reinterpret_cast<const bf16x8*>(
                            &VsG[(dh * 32 + ql) * 72 + c * 16 + hB * 8]);
                        acc[dh] = __builtin_amdgcn_mfma_f32_32x32x16_bf16(vf, pb, acc[dh], 0, 0, 0);
                    }
                }
                __builtin_amdgcn_s_setprio(0);
            }
            __syncthreads();
            kv0 += 128;
        }

        const int fidx = (wq * 64 + lane) * 36;
        if (g == 1) {
#pragma unroll
            for (int dh = 0; dh < 2; dh++)
#pragma unroll
                for (int r = 0; r < 16; r++) fm[fidx + dh * 16 + r] = acc[dh][r];
            fm[fidx + 32] = m_;
            fm[fidx + 33] = l_;
        }
        __syncthreads();
        float o_sc1 = 0.f, o_sc2 = 0.f, linv = 0.f;
        float acc2[32];
        if (g == 0) {
            const float m2 = fm[fidx + 32];
            const float l2 = fm[fidx + 33];
            const float mm = fmaxf(m_, m2);
            o_sc1 = exp2f(m_ - mm);
            o_sc2 = exp2f(m2 - mm);
            const float lt = l_ * o_sc1 + l2 * o_sc2;
            linv = 1.0f / lt;
#pragma unroll
            for (int dh = 0; dh < 2; dh++)
#pragma unroll
                for (int r = 0; r < 16; r++) acc2[dh * 16 + r] = fm[fidx + dh * 16 + r];
        }
        __syncthreads();
        if (g == 0) {
            const int lrow = wq * 32 + ql;
#pragma unroll
            for (int dh = 0; dh < 2; dh++)
#pragma unroll
                for (int rp = 0; rp < 16; rp += 2) {
                    const int d = (rp & 3) + 8 * (rp >> 2) + 4 * hB + 32 * dh;
                    const float v0 = (acc[dh][rp]     * o_sc1 + acc2[dh * 16 + rp]     * o_sc2) * linv;
                    const float v1 = (acc[dh][rp + 1] * o_sc1 + acc2[dh * 16 + rp + 1] * o_sc2) * linv;
                    *reinterpret_cast<u32*>(&smem[lrow * 72 + d]) = pkbf(v0, v1);
                }
        }
        __syncthreads();
        {
            const int row = tid >> 2;
            const int ch = tid & 3;
#pragma unroll
            for (int p = 0; p < 2; ++p) {
                uint4 ov = *reinterpret_cast<const uint4*>(&smem[row * 72 + (ch + 4 * p) * 8]);
                *reinterpret_cast<uint4*>(&Y[(size_t)(b * TT + q0 + row) * CC + hh * DD + (ch + 4 * p) * 8]) = ov;
            }
        }
        __syncthreads();
    }
}

extern "C" void kernel_launch(void* const* d_in, const int* in_sizes, int n_in,
                              void* d_out, int out_size, void* d_ws, size_t ws_size,
                              hipStream_t stream)
{
    const float* x     = (const float*)d_in[0];
    const float* Wqkv  = (const float*)d_in[1];
    const float* bqkv  = (const float*)d_in[2];
    const float* Wproj = (const float*)d_in[3];
    const float* bproj = (const float*)d_in[4];
    float* out = (float*)d_out;

    u16* ws     = (u16*)d_ws;
    u16* xb     = ws;                                  // 4M u16
    u16* wqkvb  = xb     + (size_t)MR * CC;            // 3M
    u16* wprojb = wqkvb  + (size_t)NQ * CC;            // 1M
    u16* Vc     = wprojb + (size_t)CC * CC;            // 4M  (B,T,C) V section
    u16* Qr     = Vc     + (size_t)MR * CC;            // 4M  (B,H,T,D)
    u16* Kr     = Qr     + (size_t)BB * HH * TT * DD;  // 4M
    u16* Vtg    = Kr     + (size_t)BB * HH * TT * DD;  // 4M  (B,H,D,T)
    u16* yb     = Vtg    + (size_t)BB * HH * TT * DD;  // 4M
    float2* tab = (float2*)(yb + (size_t)MR * CC);     // 2048*32 float2
    u32* ctr    = (u32*)(tab + (size_t)TT * 32);

    cvt_all<<<dim3(8448), 256, 0, stream>>>(x, Wqkv, Wproj, xb, wqkvb, wprojb, tab, ctr);

    gemm_qkv<<<dim3(24, 32), 256, 0, stream>>>(xb, wqkvb, bqkv, tab, Qr, Kr, Vc);

    vtrans<<<dim3(TT / 64, BB * HH), 64, 0, stream>>>(Vc, Vtg);

    attn_fwd<<<dim3(768), 512, 0, stream>>>(Qr, Kr, Vtg, yb, ctr);

    gemm_proj<<<dim3(8, 64), 256, 0, stream>>>(yb, wprojb, bproj, out);
}